// Round 10
// baseline (164.036 us; speedup 1.0000x reference)
//
#include <hip/hip_runtime.h>
#include <hip/hip_bf16.h>

#define T 8192
#define D 128
#define NSPLIT 12
#define BN 64
#define BM 128              /* rows per workgroup */
#define LOG2E 1.44269504088896f

typedef _Float16 half4_t __attribute__((ext_vector_type(4)));
typedef _Float16 half8_t __attribute__((ext_vector_type(8)));
typedef float floatx4 __attribute__((ext_vector_type(4)));

// ---------------------------------------------------------------------------
// prep: q16 = f16(question), qT16 = transpose, cm16 = f16(ctx*w_m*log2e),
// qq2[j] = (question[j].w_q)*log2e.  Fully coalesced float4 lanes.
// grid 256 (32 rows/block), block 256
// ---------------------------------------------------------------------------
__global__ void prep_kernel(const float* __restrict__ x, const float* __restrict__ kern,
                            _Float16* __restrict__ q16, _Float16* __restrict__ qT16,
                            _Float16* __restrict__ cm16, float* __restrict__ qq2) {
    const float* context  = x;
    const float* question = x + (size_t)T * D;
    const float* wq = kern + D;
    const float* wm = kern + 2 * D;
    __shared__ __align__(16) _Float16 tile[32][136];
    int j0 = blockIdx.x * 32;
    int t = threadIdx.x;
    int c4 = t & 31;       // float4 index within row (0..31)
    int rsub = t >> 5;     // 0..7
    float4 wqv = ((const float4*)wq)[c4];
    float4 wmv = ((const float4*)wm)[c4];
    for (int p = 0; p < 4; ++p) {
        int row = p * 8 + rsub;
        float4 q = ((const float4*)(question + (size_t)(j0 + row) * D))[c4];
        float4 c = ((const float4*)(context  + (size_t)(j0 + row) * D))[c4];
        half4_t qh;
        qh[0] = (_Float16)q.x; qh[1] = (_Float16)q.y; qh[2] = (_Float16)q.z; qh[3] = (_Float16)q.w;
        *(half4_t*)(q16 + (size_t)(j0 + row) * D + c4 * 4) = qh;
        *(half4_t*)&tile[row][c4 * 4] = qh;
        half4_t ch;
        ch[0] = (_Float16)(c.x * wmv.x * LOG2E); ch[1] = (_Float16)(c.y * wmv.y * LOG2E);
        ch[2] = (_Float16)(c.z * wmv.z * LOG2E); ch[3] = (_Float16)(c.w * wmv.w * LOG2E);
        *(half4_t*)(cm16 + (size_t)(j0 + row) * D + c4 * 4) = ch;
        float s = q.x * wqv.x + q.y * wqv.y + q.z * wqv.z + q.w * wqv.w;
        for (int dx = 1; dx <= 16; dx <<= 1) s += __shfl_xor(s, dx);
        if (c4 == 0) qq2[j0 + row] = s * LOG2E;
    }
    __syncthreads();
    for (int p = 0; p < 2; ++p) {
        int chunk = t + p * 256;
        int d = chunk >> 2, jo = (chunk & 3) * 8;
        half8_t v;
        for (int s2 = 0; s2 < 8; ++s2) v[s2] = tile[jo + s2][d];
        *(half8_t*)(qT16 + (size_t)d * T + j0 + jo) = v;
    }
}

// ---------------------------------------------------------------------------
// flash (R8 structure, 3 blocks/CU): low register demand — no prefetch regs,
// qfrag reloaded from L2-resident cm16 every iteration (asm barrier blocks
// LICM re-hoisting).  St = K (Q*wm)^T; P's C-layout IS the A-operand layout
// of 16x16x16 MFMA.  Vt interleave: phys pr*32+quad*8+h*4+r holds key
// (2pr+h)*16+quad*4+r -> PV b-operands are ds_read_b128.  Normalized O
// partials (O/l) in fp8 e4m3.  Uneven splits: 128 BN-tiles = 8x11 + 4x10.
// grid 768 = 64 row-blocks x 12 j-splits -> exactly 3 blocks/CU.
// ---------------------------------------------------------------------------
__global__ __launch_bounds__(256, 3)
void flash_kernel(const _Float16* __restrict__ q16, const _Float16* __restrict__ qT16,
                  const _Float16* __restrict__ cm16, const float* __restrict__ qq2,
                  unsigned char* __restrict__ Opart, float* __restrict__ mpart,
                  float* __restrict__ lpart) {
    __shared__ __align__(16) _Float16 Kt[64][144];   // [key][d], stride 144h
    __shared__ __align__(16) _Float16 Vt[128][72];   // [d][phys key], stride 72h
    __shared__ __align__(16) float qqs[704];         // biases (<=11 tiles)

    int bx = blockIdx.x;
    int rb = bx / NSPLIT;
    int sp = bx % NSPLIT;
    int tid = threadIdx.x;
    int wave = tid >> 6;
    int lane = tid & 63;
    int quad = lane >> 4;
    int l15 = lane & 15;
    int rbase = rb * BM + wave * 32;

    // uneven split: tiles [tstart, tstart+tcount) of the 128 BN-tiles
    int tcount = 10 + (sp < 8 ? 1 : 0);
    int tstart = sp * 10 + (sp < 8 ? sp : 8);
    int jbase = tstart * BN;

    if (tid < tcount * 16)
        ((float4*)qqs)[tid] = ((const float4*)(qq2 + jbase))[tid];

    size_t qoff = (size_t)(rbase + l15) * D + quad * 8;   // lane's Q-row offset

    floatx4 acc[2][8];
    for (int mt = 0; mt < 2; ++mt)
        for (int nt = 0; nt < 8; ++nt)
            for (int r = 0; r < 4; ++r) acc[mt][nt][r] = 0.f;
    float m_run[2] = {-INFINITY, -INFINITY};
    float l_run[2] = {0.f, 0.f};

    for (int it = 0; it < tcount; ++it) {
        int j0 = jbase + it * BN;

        // ---- qfrag reload from L2 (asm barrier defeats loop-invariant hoist);
        //      issued before staging so latency overlaps ds_writes+barrier ----
        const _Float16* qb = cm16;
        asm volatile("" : "+v"(qb));
        half8_t qf0[4], qf1[4];
        for (int ks = 0; ks < 4; ++ks) {
            qf0[ks] = *(const half8_t*)(qb + qoff + ks * 32);
            qf1[ks] = *(const half8_t*)(qb + qoff + 16 * D + ks * 32);
        }

        // ---- stage K tile [64 keys][128 d] ----
        for (int k = 0; k < 4; ++k) {
            int idx = tid + k * 256;
            *(half8_t*)&Kt[idx >> 4][(idx & 15) * 8] =
                *(const half8_t*)(q16 + (size_t)(j0 + (idx >> 4)) * D + (idx & 15) * 8);
        }
        // ---- stage V^T tile [128 d][64 keys] interleaved ----
        for (int k = 0; k < 4; ++k) {
            int idx = tid + k * 256;
            int dr = idx >> 3, c8 = idx & 7;
            half8_t v = *(const half8_t*)(qT16 + (size_t)dr * T + j0 + c8 * 8);
            int ph0 = (c8 >> 2) * 32 + (c8 & 1) * 16 + ((c8 >> 1) & 1) * 4;
            half4_t lo, hi;
            lo[0] = v[0]; lo[1] = v[1]; lo[2] = v[2]; lo[3] = v[3];
            hi[0] = v[4]; hi[1] = v[5]; hi[2] = v[6]; hi[3] = v[7];
            *(half4_t*)&Vt[dr][ph0]     = lo;
            *(half4_t*)&Vt[dr][ph0 + 8] = hi;
        }
        __syncthreads();

        // ---- St = K Qm^T + bias (bias as C-init): key=16jt+4quad+r, query=16mt+l15 ----
        floatx4 St[2][4];
        for (int jt = 0; jt < 4; ++jt) {
            float4 bias = *(const float4*)&qqs[it * 64 + jt * 16 + quad * 4];
            St[0][jt][0] = bias.x; St[0][jt][1] = bias.y; St[0][jt][2] = bias.z; St[0][jt][3] = bias.w;
            St[1][jt][0] = bias.x; St[1][jt][1] = bias.y; St[1][jt][2] = bias.z; St[1][jt][3] = bias.w;
        }
        for (int ks = 0; ks < 4; ++ks)
            for (int jt = 0; jt < 4; ++jt) {
                half8_t a = *(const half8_t*)&Kt[jt * 16 + l15][ks * 32 + quad * 8];
                St[0][jt] = __builtin_amdgcn_mfma_f32_16x16x32_f16(a, qf0[ks], St[0][jt], 0, 0, 0);
                St[1][jt] = __builtin_amdgcn_mfma_f32_16x16x32_f16(a, qf1[ks], St[1][jt], 0, 0, 0);
            }

        // ---- online softmax ----
        half4_t apv[2][4];
        float alpha[2];
        for (int mt = 0; mt < 2; ++mt) {
            float mx = St[mt][0][0];
            for (int jt = 0; jt < 4; ++jt)
                for (int r = 0; r < 4; ++r) mx = fmaxf(mx, St[mt][jt][r]);
            mx = fmaxf(mx, __shfl_xor(mx, 16));
            mx = fmaxf(mx, __shfl_xor(mx, 32));
            float mnew = fmaxf(m_run[mt], mx);
            alpha[mt] = __builtin_amdgcn_exp2f(m_run[mt] - mnew);
            m_run[mt] = mnew;
            float ps = 0.f;
            for (int jt = 0; jt < 4; ++jt) {
                float p0 = __builtin_amdgcn_exp2f(St[mt][jt][0] - mnew);
                float p1 = __builtin_amdgcn_exp2f(St[mt][jt][1] - mnew);
                float p2 = __builtin_amdgcn_exp2f(St[mt][jt][2] - mnew);
                float p3 = __builtin_amdgcn_exp2f(St[mt][jt][3] - mnew);
                ps += (p0 + p1) + (p2 + p3);
                apv[mt][jt][0] = (_Float16)p0;
                apv[mt][jt][1] = (_Float16)p1;
                apv[mt][jt][2] = (_Float16)p2;
                apv[mt][jt][3] = (_Float16)p3;
            }
            ps += __shfl_xor(ps, 16);
            ps += __shfl_xor(ps, 32);
            l_run[mt] = l_run[mt] * alpha[mt] + ps;
        }
        for (int mt = 0; mt < 2; ++mt) {
            float aT[4];
            for (int r = 0; r < 4; ++r)
                aT[r] = __shfl(alpha[mt], quad * 4 + r);
            for (int nt = 0; nt < 8; ++nt)
                for (int r = 0; r < 4; ++r) acc[mt][nt][r] *= aT[r];
        }

        // ---- O += P V via 16x16x16; b128 V reads, lo/hi half4 per jt pair ----
        for (int pr = 0; pr < 2; ++pr) {
            for (int nt = 0; nt < 8; ++nt) {
                half8_t bb = *(const half8_t*)&Vt[nt * 16 + l15][pr * 32 + quad * 8];
                half4_t b0, b1;
                b0[0] = bb[0]; b0[1] = bb[1]; b0[2] = bb[2]; b0[3] = bb[3];
                b1[0] = bb[4]; b1[1] = bb[5]; b1[2] = bb[6]; b1[3] = bb[7];
                int jt0 = pr * 2, jt1 = pr * 2 + 1;
                acc[0][nt] = __builtin_amdgcn_mfma_f32_16x16x16f16(apv[0][jt0], b0, acc[0][nt], 0, 0, 0);
                acc[1][nt] = __builtin_amdgcn_mfma_f32_16x16x16f16(apv[1][jt0], b0, acc[1][nt], 0, 0, 0);
                acc[0][nt] = __builtin_amdgcn_mfma_f32_16x16x16f16(apv[0][jt1], b1, acc[0][nt], 0, 0, 0);
                acc[1][nt] = __builtin_amdgcn_mfma_f32_16x16x16f16(apv[1][jt1], b1, acc[1][nt], 0, 0, 0);
            }
        }
        __syncthreads();
    }

    // ---- finalize: write normalized O (O/l) as fp8 e4m3, plus m,l ----
    for (int mt = 0; mt < 2; ++mt) {
        if (quad == 0) {
            int iq = rbase + mt * 16 + l15;
            mpart[(size_t)sp * T + iq] = m_run[mt];
            lpart[(size_t)sp * T + iq] = l_run[mt];
        }
        float rinv[4];
        for (int r = 0; r < 4; ++r)
            rinv[r] = 1.0f / __shfl(l_run[mt], quad * 4 + r);
        int i = rbase + mt * 16 + quad * 4;
        for (int nt = 0; nt < 8; ++nt)
            for (int r = 0; r < 4; ++r) {
                float v = acc[mt][nt][r] * rinv[r];
                int p = __builtin_amdgcn_cvt_pk_fp8_f32(v, v, 0, false);
                Opart[((size_t)sp * T + (i + r)) * D + nt * 16 + l15] = (unsigned char)(p & 0xFF);
            }
    }
}

// ---------------------------------------------------------------------------
// merge 12 fp8 normalized split partials -> U_A (fp32), linv[i] = 1/L_i.
// grid 512, block 256
// ---------------------------------------------------------------------------
__global__ void merge_kernel(const unsigned char* __restrict__ Opart, const float* __restrict__ mpart,
                             const float* __restrict__ lpart, float* __restrict__ U_A,
                             float* __restrict__ linv) {
    int t = threadIdx.x;
    int i = blockIdx.x * 16 + (t >> 4);
    int c = t & 15;
    float mp[NSPLIT];
    float mstar = -INFINITY;
    for (int sp = 0; sp < NSPLIT; ++sp) {
        mp[sp] = mpart[(size_t)sp * T + i];
        mstar = fmaxf(mstar, mp[sp]);
    }
    float L = 0.f;
    float u[8];
    for (int k = 0; k < 8; ++k) u[k] = 0.f;
    int d0 = c * 8;
    for (int sp = 0; sp < NSPLIT; ++sp) {
        float w = __builtin_amdgcn_exp2f(mp[sp] - mstar) * lpart[(size_t)sp * T + i];
        L += w;
        uint2 ow = *(const uint2*)(Opart + ((size_t)sp * T + i) * D + d0);
        u[0] += __builtin_amdgcn_cvt_f32_fp8(ow.x, 0) * w;
        u[1] += __builtin_amdgcn_cvt_f32_fp8(ow.x, 1) * w;
        u[2] += __builtin_amdgcn_cvt_f32_fp8(ow.x, 2) * w;
        u[3] += __builtin_amdgcn_cvt_f32_fp8(ow.x, 3) * w;
        u[4] += __builtin_amdgcn_cvt_f32_fp8(ow.y, 0) * w;
        u[5] += __builtin_amdgcn_cvt_f32_fp8(ow.y, 1) * w;
        u[6] += __builtin_amdgcn_cvt_f32_fp8(ow.y, 2) * w;
        u[7] += __builtin_amdgcn_cvt_f32_fp8(ow.y, 3) * w;
    }
    float invL = 1.0f / L;
    float4 s0 = make_float4(u[0] * invL, u[1] * invL, u[2] * invL, u[3] * invL);
    float4 s1 = make_float4(u[4] * invL, u[5] * invL, u[6] * invL, u[7] * invL);
    *(float4*)(U_A + (size_t)i * D + d0) = s0;
    *(float4*)(U_A + (size_t)i * D + d0 + 4) = s1;
    if (c == 0) linv[i] = invL;
}

// ---------------------------------------------------------------------------
// h partials then reduce.  grid 64 / grid 1
// ---------------------------------------------------------------------------
__global__ void hsum_part_kernel(const float* __restrict__ x, const float* __restrict__ linv,
                                 float* __restrict__ hpart) {
    const float* context = x;
    int t = threadIdx.x;
    int d = t & 127, g = t >> 7;
    int i0 = blockIdx.x * 128 + g * 64;
    float s = 0.f;
    for (int k = 0; k < 64; ++k)
        s += context[(size_t)(i0 + k) * D + d] * linv[i0 + k];
    hpart[(size_t)(blockIdx.x * 2 + g) * 128 + d] = s;
}

__global__ void hreduce_kernel(const float* __restrict__ hpart, float* __restrict__ h) {
    int d = threadIdx.x;  // 0..127
    float s = 0.f;
    for (int k = 0; k < 128; ++k) s += hpart[(size_t)k * 128 + d];
    h[d] = s;
}

// ---------------------------------------------------------------------------
// assemble G = [ctx, U_A, ctx*U_A, ctx*h]   grid 4096, block 256, float4/thread
// ---------------------------------------------------------------------------
__global__ void assemble_kernel(const float* __restrict__ x, const float* __restrict__ U_A,
                                const float* __restrict__ h, float* __restrict__ out) {
    const float* context = x;
    int gid = blockIdx.x * 256 + threadIdx.x;
    int base = gid * 4;
    int i = base >> 9;
    int c = base & 511;
    int seg = c >> 7, d = c & 127;
    float4 r;
    if (seg == 0) {
        r = *(const float4*)(context + (size_t)i * D + d);
    } else if (seg == 1) {
        r = *(const float4*)(U_A + (size_t)i * D + d);
    } else if (seg == 2) {
        float4 a = *(const float4*)(context + (size_t)i * D + d);
        float4 b = *(const float4*)(U_A + (size_t)i * D + d);
        r = make_float4(a.x * b.x, a.y * b.y, a.z * b.z, a.w * b.w);
    } else {
        float4 a = *(const float4*)(context + (size_t)i * D + d);
        float4 b = *(const float4*)(h + d);
        r = make_float4(a.x * b.x, a.y * b.y, a.z * b.z, a.w * b.w);
    }
    *(float4*)(out + base) = r;
}

// ---------------------------------------------------------------------------
extern "C" void kernel_launch(void* const* d_in, const int* in_sizes, int n_in,
                              void* d_out, int out_size, void* d_ws, size_t ws_size,
                              hipStream_t stream) {
    const float* x = (const float*)d_in[0];
    const float* kern = (const float*)d_in[1];
    float* out = (float*)d_out;

    char* w = (char*)d_ws;
    size_t off = 0;
    _Float16* q16  = (_Float16*)(w + off); off += (size_t)T * D * 2;   // 2 MB
    _Float16* qT16 = (_Float16*)(w + off); off += (size_t)T * D * 2;   // 2 MB
    _Float16* cm16 = (_Float16*)(w + off); off += (size_t)T * D * 2;   // 2 MB
    float* qq2   = (float*)(w + off); off += (size_t)T * 4;            // 32 KB
    float* mpart = (float*)(w + off); off += (size_t)NSPLIT * T * 4;   // 384 KB
    float* lpart = (float*)(w + off); off += (size_t)NSPLIT * T * 4;   // 384 KB
    float* U_A   = (float*)(w + off); off += (size_t)T * D * 4;        // 4 MB
    float* linv  = (float*)(w + off); off += (size_t)T * 4;            // 32 KB
    float* hpart = (float*)(w + off); off += (size_t)128 * 128 * 4;    // 64 KB
    float* h     = (float*)(w + off); off += (size_t)D * 4;

    // d_out doubles as fp8 split-partial scratch: 12 * T * D * 1B = 12 MB <= 16 MB
    unsigned char* Opart = (unsigned char*)d_out;

    prep_kernel<<<256, 256, 0, stream>>>(x, kern, q16, qT16, cm16, qq2);
    flash_kernel<<<768, 256, 0, stream>>>(q16, qT16, cm16, qq2, Opart, mpart, lpart);
    merge_kernel<<<512, 256, 0, stream>>>(Opart, mpart, lpart, U_A, linv);
    hsum_part_kernel<<<64, 256, 0, stream>>>(x, linv, hpart);
    hreduce_kernel<<<1, 128, 0, stream>>>(hpart, h);
    assemble_kernel<<<4096, 256, 0, stream>>>(x, U_A, h, out);
}

// Round 11
// 136.322 us; speedup vs baseline: 1.2033x; 1.2033x over previous
//
#include <hip/hip_runtime.h>
#include <hip/hip_bf16.h>

#define T 8192
#define D 128
#define NSPLIT 8
#define JLEN (T / NSPLIT)   /* 1024 */
#define BN 64
#define NITER (JLEN / BN)   /* 16 */
#define BM 128              /* rows per workgroup */
#define LOG2E 1.44269504088896f

typedef _Float16 half4_t __attribute__((ext_vector_type(4)));
typedef _Float16 half8_t __attribute__((ext_vector_type(8)));
typedef float floatx4 __attribute__((ext_vector_type(4)));

// ---------------------------------------------------------------------------
// prep: q16 = f16(question), qT16 = transpose, cm16 = f16(ctx*w_m*log2e),
// qq2[j] = (question[j].w_q)*log2e.  Fully coalesced float4 lanes.
// grid 256 (32 rows/block), block 256
// ---------------------------------------------------------------------------
__global__ void prep_kernel(const float* __restrict__ x, const float* __restrict__ kern,
                            _Float16* __restrict__ q16, _Float16* __restrict__ qT16,
                            _Float16* __restrict__ cm16, float* __restrict__ qq2) {
    const float* context  = x;
    const float* question = x + (size_t)T * D;
    const float* wq = kern + D;
    const float* wm = kern + 2 * D;
    __shared__ __align__(16) _Float16 tile[32][136];
    int j0 = blockIdx.x * 32;
    int t = threadIdx.x;
    int c4 = t & 31;       // float4 index within row (0..31)
    int rsub = t >> 5;     // 0..7
    float4 wqv = ((const float4*)wq)[c4];
    float4 wmv = ((const float4*)wm)[c4];
    for (int p = 0; p < 4; ++p) {
        int row = p * 8 + rsub;
        float4 q = ((const float4*)(question + (size_t)(j0 + row) * D))[c4];
        float4 c = ((const float4*)(context  + (size_t)(j0 + row) * D))[c4];
        half4_t qh;
        qh[0] = (_Float16)q.x; qh[1] = (_Float16)q.y; qh[2] = (_Float16)q.z; qh[3] = (_Float16)q.w;
        *(half4_t*)(q16 + (size_t)(j0 + row) * D + c4 * 4) = qh;
        *(half4_t*)&tile[row][c4 * 4] = qh;
        half4_t ch;
        ch[0] = (_Float16)(c.x * wmv.x * LOG2E); ch[1] = (_Float16)(c.y * wmv.y * LOG2E);
        ch[2] = (_Float16)(c.z * wmv.z * LOG2E); ch[3] = (_Float16)(c.w * wmv.w * LOG2E);
        *(half4_t*)(cm16 + (size_t)(j0 + row) * D + c4 * 4) = ch;
        float s = q.x * wqv.x + q.y * wqv.y + q.z * wqv.z + q.w * wqv.w;
        for (int dx = 1; dx <= 16; dx <<= 1) s += __shfl_xor(s, dx);
        if (c4 == 0) qq2[j0 + row] = s * LOG2E;
    }
    __syncthreads();
    for (int p = 0; p < 2; ++p) {
        int chunk = t + p * 256;
        int d = chunk >> 2, jo = (chunk & 3) * 8;
        half8_t v;
        for (int s2 = 0; s2 < 8; ++s2) v[s2] = tile[jo + s2][d];
        *(half8_t*)(qT16 + (size_t)d * T + j0 + jo) = v;
    }
}

// ---------------------------------------------------------------------------
// flash (R8 + deferred-PV software pipeline):
// At iter i: stage tiles, compute QK_i (MFMA), then PV_{i-1} (MFMA,
// independent — P/alpha held in regs, V in double-buffered Vt), then
// softmax_i (VALU) overlapping PV execution.  Breaks the per-iter serial
// QK->softmax->PV chain that capped both pipes at ~35%.
// Vt interleave: phys pr*32+quad*8+h*4+r holds key (2pr+h)*16+quad*4+r ->
// PV b-operands are ds_read_b128.  Normalized O partials (O/l) in fp8 e4m3.
// grid 512 = 64 row-blocks x 8 j-splits, block 256 (4 waves, 32 rows/wave)
// ---------------------------------------------------------------------------
__global__ __launch_bounds__(256, 2)
void flash_kernel(const _Float16* __restrict__ q16, const _Float16* __restrict__ qT16,
                  const _Float16* __restrict__ cm16, const float* __restrict__ qq2,
                  unsigned char* __restrict__ Opart, float* __restrict__ mpart,
                  float* __restrict__ lpart) {
    __shared__ __align__(16) _Float16 Kt[64][144];     // [key][d], stride 144h
    __shared__ __align__(16) _Float16 Vt[2][128][72];  // [buf][d][phys key]
    __shared__ __align__(16) float qqs[JLEN];          // biases for this split (4KB)

    int bx = blockIdx.x;
    int rb = bx >> 3;
    int sp = bx & 7;
    int tid = threadIdx.x;
    int wave = tid >> 6;
    int lane = tid & 63;
    int quad = lane >> 4;
    int l15 = lane & 15;
    int rbase = rb * BM + wave * 32;

    ((float4*)qqs)[tid] = ((const float4*)(qq2 + (size_t)sp * JLEN))[tid];

    half8_t qfrag[2][4];
    for (int mt = 0; mt < 2; ++mt)
        for (int ks = 0; ks < 4; ++ks)
            qfrag[mt][ks] = *(const half8_t*)(cm16 + (size_t)(rbase + mt * 16 + l15) * D
                                              + ks * 32 + quad * 8);

    floatx4 acc[2][8];
    for (int mt = 0; mt < 2; ++mt)
        for (int nt = 0; nt < 8; ++nt)
            for (int r = 0; r < 4; ++r) acc[mt][nt][r] = 0.f;
    float m_run[2] = {-INFINITY, -INFINITY};
    float l_run[2] = {0.f, 0.f};

    // deferred-PV state (tile i-1's P and alpha)
    half4_t apvP[2][4];
    float alphaP[2];

    // prefetch iter 0 tiles into registers (16B contiguous loads)
    half8_t kreg[4], vreg[4];
    {
        int j0 = sp * JLEN;
        for (int k = 0; k < 4; ++k) {
            int idx = tid + k * 256;
            kreg[k] = *(const half8_t*)(q16 + (size_t)(j0 + (idx >> 4)) * D + (idx & 15) * 8);
            vreg[k] = *(const half8_t*)(qT16 + (size_t)(idx >> 3) * T + j0 + (idx & 7) * 8);
        }
    }

    for (int it = 0; it < NITER; ++it) {
        int vb = it & 1;
        // ---- commit prefetched tiles to LDS ----
        for (int k = 0; k < 4; ++k) {
            int idx = tid + k * 256;
            *(half8_t*)&Kt[idx >> 4][(idx & 15) * 8] = kreg[k];
        }
        for (int k = 0; k < 4; ++k) {
            int idx = tid + k * 256;
            int dr = idx >> 3, c8 = idx & 7;
            int ph0 = (c8 >> 2) * 32 + (c8 & 1) * 16 + ((c8 >> 1) & 1) * 4;
            half4_t lo, hi;
            lo[0] = vreg[k][0]; lo[1] = vreg[k][1]; lo[2] = vreg[k][2]; lo[3] = vreg[k][3];
            hi[0] = vreg[k][4]; hi[1] = vreg[k][5]; hi[2] = vreg[k][6]; hi[3] = vreg[k][7];
            *(half4_t*)&Vt[vb][dr][ph0]     = lo;
            *(half4_t*)&Vt[vb][dr][ph0 + 8] = hi;
        }
        __syncthreads();

        // ---- issue next iteration's global loads (latency overlaps compute) ----
        if (it + 1 < NITER) {
            int j0n = sp * JLEN + (it + 1) * BN;
            for (int k = 0; k < 4; ++k) {
                int idx = tid + k * 256;
                kreg[k] = *(const half8_t*)(q16 + (size_t)(j0n + (idx >> 4)) * D + (idx & 15) * 8);
                vreg[k] = *(const half8_t*)(qT16 + (size_t)(idx >> 3) * T + j0n + (idx & 7) * 8);
            }
        }

        // ---- St = K Qm^T + bias (bias as C-init): key=16jt+4quad+r, query=16mt+l15 ----
        floatx4 St[2][4];
        for (int jt = 0; jt < 4; ++jt) {
            float4 bias = *(const float4*)&qqs[it * 64 + jt * 16 + quad * 4];
            St[0][jt][0] = bias.x; St[0][jt][1] = bias.y; St[0][jt][2] = bias.z; St[0][jt][3] = bias.w;
            St[1][jt][0] = bias.x; St[1][jt][1] = bias.y; St[1][jt][2] = bias.z; St[1][jt][3] = bias.w;
        }
        for (int ks = 0; ks < 4; ++ks)
            for (int jt = 0; jt < 4; ++jt) {
                half8_t a = *(const half8_t*)&Kt[jt * 16 + l15][ks * 32 + quad * 8];
                St[0][jt] = __builtin_amdgcn_mfma_f32_16x16x32_f16(a, qfrag[0][ks], St[0][jt], 0, 0, 0);
                St[1][jt] = __builtin_amdgcn_mfma_f32_16x16x32_f16(a, qfrag[1][ks], St[1][jt], 0, 0, 0);
            }

        // ---- deferred PV of tile it-1 (independent of St — overlaps QK/softmax) ----
        if (it > 0) {
            int pb = vb ^ 1;
            for (int mt = 0; mt < 2; ++mt) {
                float aT[4];
                for (int r = 0; r < 4; ++r)
                    aT[r] = __shfl(alphaP[mt], quad * 4 + r);
                for (int nt = 0; nt < 8; ++nt)
                    for (int r = 0; r < 4; ++r) acc[mt][nt][r] *= aT[r];
            }
            for (int pr = 0; pr < 2; ++pr) {
                for (int nt = 0; nt < 8; ++nt) {
                    half8_t bb = *(const half8_t*)&Vt[pb][nt * 16 + l15][pr * 32 + quad * 8];
                    half4_t b0, b1;
                    b0[0] = bb[0]; b0[1] = bb[1]; b0[2] = bb[2]; b0[3] = bb[3];
                    b1[0] = bb[4]; b1[1] = bb[5]; b1[2] = bb[6]; b1[3] = bb[7];
                    int jt0 = pr * 2, jt1 = pr * 2 + 1;
                    acc[0][nt] = __builtin_amdgcn_mfma_f32_16x16x16f16(apvP[0][jt0], b0, acc[0][nt], 0, 0, 0);
                    acc[1][nt] = __builtin_amdgcn_mfma_f32_16x16x16f16(apvP[1][jt0], b0, acc[1][nt], 0, 0, 0);
                    acc[0][nt] = __builtin_amdgcn_mfma_f32_16x16x16f16(apvP[0][jt1], b1, acc[0][nt], 0, 0, 0);
                    acc[1][nt] = __builtin_amdgcn_mfma_f32_16x16x16f16(apvP[1][jt1], b1, acc[1][nt], 0, 0, 0);
                }
            }
        }

        // ---- online softmax for tile it -> apvP/alphaP (consumed next iter) ----
        for (int mt = 0; mt < 2; ++mt) {
            float mx = St[mt][0][0];
            for (int jt = 0; jt < 4; ++jt)
                for (int r = 0; r < 4; ++r) mx = fmaxf(mx, St[mt][jt][r]);
            mx = fmaxf(mx, __shfl_xor(mx, 16));
            mx = fmaxf(mx, __shfl_xor(mx, 32));
            float mnew = fmaxf(m_run[mt], mx);
            alphaP[mt] = __builtin_amdgcn_exp2f(m_run[mt] - mnew);
            m_run[mt] = mnew;
            float ps = 0.f;
            for (int jt = 0; jt < 4; ++jt) {
                float p0 = __builtin_amdgcn_exp2f(St[mt][jt][0] - mnew);
                float p1 = __builtin_amdgcn_exp2f(St[mt][jt][1] - mnew);
                float p2 = __builtin_amdgcn_exp2f(St[mt][jt][2] - mnew);
                float p3 = __builtin_amdgcn_exp2f(St[mt][jt][3] - mnew);
                ps += (p0 + p1) + (p2 + p3);
                apvP[mt][jt][0] = (_Float16)p0;
                apvP[mt][jt][1] = (_Float16)p1;
                apvP[mt][jt][2] = (_Float16)p2;
                apvP[mt][jt][3] = (_Float16)p3;
            }
            ps += __shfl_xor(ps, 16);
            ps += __shfl_xor(ps, 32);
            l_run[mt] = l_run[mt] * alphaP[mt] + ps;
        }
        __syncthreads();
    }

    // ---- flush final tile's PV ----
    {
        int pb = (NITER - 1) & 1;
        for (int mt = 0; mt < 2; ++mt) {
            float aT[4];
            for (int r = 0; r < 4; ++r)
                aT[r] = __shfl(alphaP[mt], quad * 4 + r);
            for (int nt = 0; nt < 8; ++nt)
                for (int r = 0; r < 4; ++r) acc[mt][nt][r] *= aT[r];
        }
        for (int pr = 0; pr < 2; ++pr) {
            for (int nt = 0; nt < 8; ++nt) {
                half8_t bb = *(const half8_t*)&Vt[pb][nt * 16 + l15][pr * 32 + quad * 8];
                half4_t b0, b1;
                b0[0] = bb[0]; b0[1] = bb[1]; b0[2] = bb[2]; b0[3] = bb[3];
                b1[0] = bb[4]; b1[1] = bb[5]; b1[2] = bb[6]; b1[3] = bb[7];
                int jt0 = pr * 2, jt1 = pr * 2 + 1;
                acc[0][nt] = __builtin_amdgcn_mfma_f32_16x16x16f16(apvP[0][jt0], b0, acc[0][nt], 0, 0, 0);
                acc[1][nt] = __builtin_amdgcn_mfma_f32_16x16x16f16(apvP[1][jt0], b0, acc[1][nt], 0, 0, 0);
                acc[0][nt] = __builtin_amdgcn_mfma_f32_16x16x16f16(apvP[0][jt1], b1, acc[0][nt], 0, 0, 0);
                acc[1][nt] = __builtin_amdgcn_mfma_f32_16x16x16f16(apvP[1][jt1], b1, acc[1][nt], 0, 0, 0);
            }
        }
    }

    // ---- finalize: write normalized O (O/l) as fp8 e4m3, plus m,l ----
    for (int mt = 0; mt < 2; ++mt) {
        if (quad == 0) {
            int iq = rbase + mt * 16 + l15;
            mpart[(size_t)sp * T + iq] = m_run[mt];
            lpart[(size_t)sp * T + iq] = l_run[mt];
        }
        float rinv[4];
        for (int r = 0; r < 4; ++r)
            rinv[r] = 1.0f / __shfl(l_run[mt], quad * 4 + r);
        int i = rbase + mt * 16 + quad * 4;
        for (int nt = 0; nt < 8; ++nt)
            for (int r = 0; r < 4; ++r) {
                float v = acc[mt][nt][r] * rinv[r];
                int p = __builtin_amdgcn_cvt_pk_fp8_f32(v, v, 0, false);
                Opart[((size_t)sp * T + (i + r)) * D + nt * 16 + l15] = (unsigned char)(p & 0xFF);
            }
    }
}

// ---------------------------------------------------------------------------
// merge 8 fp8 normalized split partials -> U_A (fp32), linv[i] = 1/L_i.
// grid 512, block 256
// ---------------------------------------------------------------------------
__global__ void merge_kernel(const unsigned char* __restrict__ Opart, const float* __restrict__ mpart,
                             const float* __restrict__ lpart, float* __restrict__ U_A,
                             float* __restrict__ linv) {
    int t = threadIdx.x;
    int i = blockIdx.x * 16 + (t >> 4);
    int c = t & 15;
    float mp[NSPLIT];
    float mstar = -INFINITY;
    for (int sp = 0; sp < NSPLIT; ++sp) {
        mp[sp] = mpart[(size_t)sp * T + i];
        mstar = fmaxf(mstar, mp[sp]);
    }
    float L = 0.f;
    float u[8];
    for (int k = 0; k < 8; ++k) u[k] = 0.f;
    int d0 = c * 8;
    for (int sp = 0; sp < NSPLIT; ++sp) {
        float w = __builtin_amdgcn_exp2f(mp[sp] - mstar) * lpart[(size_t)sp * T + i];
        L += w;
        uint2 ow = *(const uint2*)(Opart + ((size_t)sp * T + i) * D + d0);
        u[0] += __builtin_amdgcn_cvt_f32_fp8(ow.x, 0) * w;
        u[1] += __builtin_amdgcn_cvt_f32_fp8(ow.x, 1) * w;
        u[2] += __builtin_amdgcn_cvt_f32_fp8(ow.x, 2) * w;
        u[3] += __builtin_amdgcn_cvt_f32_fp8(ow.x, 3) * w;
        u[4] += __builtin_amdgcn_cvt_f32_fp8(ow.y, 0) * w;
        u[5] += __builtin_amdgcn_cvt_f32_fp8(ow.y, 1) * w;
        u[6] += __builtin_amdgcn_cvt_f32_fp8(ow.y, 2) * w;
        u[7] += __builtin_amdgcn_cvt_f32_fp8(ow.y, 3) * w;
    }
    float invL = 1.0f / L;
    float4 s0 = make_float4(u[0] * invL, u[1] * invL, u[2] * invL, u[3] * invL);
    float4 s1 = make_float4(u[4] * invL, u[5] * invL, u[6] * invL, u[7] * invL);
    *(float4*)(U_A + (size_t)i * D + d0) = s0;
    *(float4*)(U_A + (size_t)i * D + d0 + 4) = s1;
    if (c == 0) linv[i] = invL;
}

// ---------------------------------------------------------------------------
// h partials then reduce.  grid 64 / grid 1
// ---------------------------------------------------------------------------
__global__ void hsum_part_kernel(const float* __restrict__ x, const float* __restrict__ linv,
                                 float* __restrict__ hpart) {
    const float* context = x;
    int t = threadIdx.x;
    int d = t & 127, g = t >> 7;
    int i0 = blockIdx.x * 128 + g * 64;
    float s = 0.f;
    for (int k = 0; k < 64; ++k)
        s += context[(size_t)(i0 + k) * D + d] * linv[i0 + k];
    hpart[(size_t)(blockIdx.x * 2 + g) * 128 + d] = s;
}

__global__ void hreduce_kernel(const float* __restrict__ hpart, float* __restrict__ h) {
    int d = threadIdx.x;  // 0..127
    float s = 0.f;
    for (int k = 0; k < 128; ++k) s += hpart[(size_t)k * 128 + d];
    h[d] = s;
}

// ---------------------------------------------------------------------------
// assemble G = [ctx, U_A, ctx*U_A, ctx*h]   grid 4096, block 256, float4/thread
// ---------------------------------------------------------------------------
__global__ void assemble_kernel(const float* __restrict__ x, const float* __restrict__ U_A,
                                const float* __restrict__ h, float* __restrict__ out) {
    const float* context = x;
    int gid = blockIdx.x * 256 + threadIdx.x;
    int base = gid * 4;
    int i = base >> 9;
    int c = base & 511;
    int seg = c >> 7, d = c & 127;
    float4 r;
    if (seg == 0) {
        r = *(const float4*)(context + (size_t)i * D + d);
    } else if (seg == 1) {
        r = *(const float4*)(U_A + (size_t)i * D + d);
    } else if (seg == 2) {
        float4 a = *(const float4*)(context + (size_t)i * D + d);
        float4 b = *(const float4*)(U_A + (size_t)i * D + d);
        r = make_float4(a.x * b.x, a.y * b.y, a.z * b.z, a.w * b.w);
    } else {
        float4 a = *(const float4*)(context + (size_t)i * D + d);
        float4 b = *(const float4*)(h + d);
        r = make_float4(a.x * b.x, a.y * b.y, a.z * b.z, a.w * b.w);
    }
    *(float4*)(out + base) = r;
}

// ---------------------------------------------------------------------------
extern "C" void kernel_launch(void* const* d_in, const int* in_sizes, int n_in,
                              void* d_out, int out_size, void* d_ws, size_t ws_size,
                              hipStream_t stream) {
    const float* x = (const float*)d_in[0];
    const float* kern = (const float*)d_in[1];
    float* out = (float*)d_out;

    char* w = (char*)d_ws;
    size_t off = 0;
    _Float16* q16  = (_Float16*)(w + off); off += (size_t)T * D * 2;   // 2 MB
    _Float16* qT16 = (_Float16*)(w + off); off += (size_t)T * D * 2;   // 2 MB
    _Float16* cm16 = (_Float16*)(w + off); off += (size_t)T * D * 2;   // 2 MB
    float* qq2   = (float*)(w + off); off += (size_t)T * 4;            // 32 KB
    float* mpart = (float*)(w + off); off += (size_t)NSPLIT * T * 4;   // 256 KB
    float* lpart = (float*)(w + off); off += (size_t)NSPLIT * T * 4;   // 256 KB
    float* U_A   = (float*)(w + off); off += (size_t)T * D * 4;        // 4 MB
    float* linv  = (float*)(w + off); off += (size_t)T * 4;            // 32 KB
    float* hpart = (float*)(w + off); off += (size_t)128 * 128 * 4;    // 64 KB
    float* h     = (float*)(w + off); off += (size_t)D * 4;

    // d_out doubles as fp8 split-partial scratch: 8 * T * D * 1B = 8 MB <= 16 MB
    unsigned char* Opart = (unsigned char*)d_out;

    prep_kernel<<<256, 256, 0, stream>>>(x, kern, q16, qT16, cm16, qq2);
    flash_kernel<<<512, 256, 0, stream>>>(q16, qT16, cm16, qq2, Opart, mpart, lpart);
    merge_kernel<<<512, 256, 0, stream>>>(Opart, mpart, lpart, U_A, linv);
    hsum_part_kernel<<<64, 256, 0, stream>>>(x, linv, hpart);
    hreduce_kernel<<<1, 128, 0, stream>>>(hpart, h);
    assemble_kernel<<<4096, 256, 0, stream>>>(x, U_A, h, out);
}

// Round 12
// 133.478 us; speedup vs baseline: 1.2289x; 1.0213x over previous
//
#include <hip/hip_runtime.h>
#include <hip/hip_bf16.h>

#define T 8192
#define D 128
#define NSPLIT 8
#define JLEN (T / NSPLIT)   /* 1024 */
#define BN 64
#define NITER (JLEN / BN)   /* 16 */
#define BM 128              /* rows per workgroup */
#define LOG2E 1.44269504088896f

typedef _Float16 half4_t __attribute__((ext_vector_type(4)));
typedef _Float16 half8_t __attribute__((ext_vector_type(8)));
typedef float floatx4 __attribute__((ext_vector_type(4)));

// ---------------------------------------------------------------------------
// prep: q16 = f16(question), qT16 = transpose, cm16 = f16(ctx*w_m*log2e),
// qq2[j] = (question[j].w_q)*log2e.  Fully coalesced float4 lanes.
// grid 256 (32 rows/block), block 256
// ---------------------------------------------------------------------------
__global__ void prep_kernel(const float* __restrict__ x, const float* __restrict__ kern,
                            _Float16* __restrict__ q16, _Float16* __restrict__ qT16,
                            _Float16* __restrict__ cm16, float* __restrict__ qq2) {
    const float* context  = x;
    const float* question = x + (size_t)T * D;
    const float* wq = kern + D;
    const float* wm = kern + 2 * D;
    __shared__ __align__(16) _Float16 tile[32][136];
    int j0 = blockIdx.x * 32;
    int t = threadIdx.x;
    int c4 = t & 31;       // float4 index within row (0..31)
    int rsub = t >> 5;     // 0..7
    float4 wqv = ((const float4*)wq)[c4];
    float4 wmv = ((const float4*)wm)[c4];
    for (int p = 0; p < 4; ++p) {
        int row = p * 8 + rsub;
        float4 q = ((const float4*)(question + (size_t)(j0 + row) * D))[c4];
        float4 c = ((const float4*)(context  + (size_t)(j0 + row) * D))[c4];
        half4_t qh;
        qh[0] = (_Float16)q.x; qh[1] = (_Float16)q.y; qh[2] = (_Float16)q.z; qh[3] = (_Float16)q.w;
        *(half4_t*)(q16 + (size_t)(j0 + row) * D + c4 * 4) = qh;
        *(half4_t*)&tile[row][c4 * 4] = qh;
        half4_t ch;
        ch[0] = (_Float16)(c.x * wmv.x * LOG2E); ch[1] = (_Float16)(c.y * wmv.y * LOG2E);
        ch[2] = (_Float16)(c.z * wmv.z * LOG2E); ch[3] = (_Float16)(c.w * wmv.w * LOG2E);
        *(half4_t*)(cm16 + (size_t)(j0 + row) * D + c4 * 4) = ch;
        float s = q.x * wqv.x + q.y * wqv.y + q.z * wqv.z + q.w * wqv.w;
        for (int dx = 1; dx <= 16; dx <<= 1) s += __shfl_xor(s, dx);
        if (c4 == 0) qq2[j0 + row] = s * LOG2E;
    }
    __syncthreads();
    for (int p = 0; p < 2; ++p) {
        int chunk = t + p * 256;
        int d = chunk >> 2, jo = (chunk & 3) * 8;
        half8_t v;
        for (int s2 = 0; s2 < 8; ++s2) v[s2] = tile[jo + s2][d];
        *(half8_t*)(qT16 + (size_t)d * T + j0 + jo) = v;
    }
}

// ---------------------------------------------------------------------------
// flash (R8 structure — measured optimum): reg-prefetch staging, interleaved
// V layout, bias-as-C-init, fp8 normalized partials.
// St = K (Q*wm)^T; P's C-layout IS the A-operand layout of 16x16x16 MFMA.
// Vt interleave: phys pr*32+quad*8+h*4+r holds key (2pr+h)*16+quad*4+r, so
// PV b-operands are ds_read_b128.  Normalized O partials (O/l) in fp8 e4m3.
// grid 512 = 64 row-blocks x 8 j-splits, block 256 (4 waves, 32 rows/wave)
// NOTE: register-capped at 2 blocks/CU (124 arch + 64 AGPR); 3+ blocks/CU
// spills (R6/R7/R10) and within-wave pipeline reorders don't help because
// MFMA issue blocks its wave (R11).
// ---------------------------------------------------------------------------
__global__ __launch_bounds__(256, 2)
void flash_kernel(const _Float16* __restrict__ q16, const _Float16* __restrict__ qT16,
                  const _Float16* __restrict__ cm16, const float* __restrict__ qq2,
                  unsigned char* __restrict__ Opart, float* __restrict__ mpart,
                  float* __restrict__ lpart) {
    __shared__ __align__(16) _Float16 Kt[64][144];   // [key][d], stride 144h
    __shared__ __align__(16) _Float16 Vt[128][72];   // [d][phys key], stride 72h
    __shared__ __align__(16) float qqs[JLEN];        // biases for this split (4KB)

    int bx = blockIdx.x;
    int rb = bx >> 3;
    int sp = bx & 7;
    int tid = threadIdx.x;
    int wave = tid >> 6;
    int lane = tid & 63;
    int quad = lane >> 4;
    int l15 = lane & 15;
    int rbase = rb * BM + wave * 32;

    ((float4*)qqs)[tid] = ((const float4*)(qq2 + (size_t)sp * JLEN))[tid];

    half8_t qfrag[2][4];
    for (int mt = 0; mt < 2; ++mt)
        for (int ks = 0; ks < 4; ++ks)
            qfrag[mt][ks] = *(const half8_t*)(cm16 + (size_t)(rbase + mt * 16 + l15) * D
                                              + ks * 32 + quad * 8);

    floatx4 acc[2][8];
    for (int mt = 0; mt < 2; ++mt)
        for (int nt = 0; nt < 8; ++nt)
            for (int r = 0; r < 4; ++r) acc[mt][nt][r] = 0.f;
    float m_run[2] = {-INFINITY, -INFINITY};
    float l_run[2] = {0.f, 0.f};

    // prefetch iter 0 tiles into registers (16B contiguous loads)
    half8_t kreg[4], vreg[4];
    {
        int j0 = sp * JLEN;
        for (int k = 0; k < 4; ++k) {
            int idx = tid + k * 256;
            kreg[k] = *(const half8_t*)(q16 + (size_t)(j0 + (idx >> 4)) * D + (idx & 15) * 8);
            vreg[k] = *(const half8_t*)(qT16 + (size_t)(idx >> 3) * T + j0 + (idx & 7) * 8);
        }
    }

    for (int it = 0; it < NITER; ++it) {
        // ---- commit prefetched tiles to LDS ----
        for (int k = 0; k < 4; ++k) {
            int idx = tid + k * 256;
            *(half8_t*)&Kt[idx >> 4][(idx & 15) * 8] = kreg[k];
        }
        for (int k = 0; k < 4; ++k) {
            int idx = tid + k * 256;
            int dr = idx >> 3, c8 = idx & 7;
            int ph0 = (c8 >> 2) * 32 + (c8 & 1) * 16 + ((c8 >> 1) & 1) * 4;
            half4_t lo, hi;
            lo[0] = vreg[k][0]; lo[1] = vreg[k][1]; lo[2] = vreg[k][2]; lo[3] = vreg[k][3];
            hi[0] = vreg[k][4]; hi[1] = vreg[k][5]; hi[2] = vreg[k][6]; hi[3] = vreg[k][7];
            *(half4_t*)&Vt[dr][ph0]     = lo;
            *(half4_t*)&Vt[dr][ph0 + 8] = hi;
        }
        __syncthreads();

        // ---- issue next iteration's global loads (latency overlaps compute) ----
        if (it + 1 < NITER) {
            int j0n = sp * JLEN + (it + 1) * BN;
            for (int k = 0; k < 4; ++k) {
                int idx = tid + k * 256;
                kreg[k] = *(const half8_t*)(q16 + (size_t)(j0n + (idx >> 4)) * D + (idx & 15) * 8);
                vreg[k] = *(const half8_t*)(qT16 + (size_t)(idx >> 3) * T + j0n + (idx & 7) * 8);
            }
        }

        // ---- St = K Qm^T + bias (bias as C-init): key=16jt+4quad+r, query=16mt+l15 ----
        floatx4 St[2][4];
        for (int jt = 0; jt < 4; ++jt) {
            float4 bias = *(const float4*)&qqs[it * 64 + jt * 16 + quad * 4];
            St[0][jt][0] = bias.x; St[0][jt][1] = bias.y; St[0][jt][2] = bias.z; St[0][jt][3] = bias.w;
            St[1][jt][0] = bias.x; St[1][jt][1] = bias.y; St[1][jt][2] = bias.z; St[1][jt][3] = bias.w;
        }
        for (int ks = 0; ks < 4; ++ks)
            for (int jt = 0; jt < 4; ++jt) {
                half8_t a = *(const half8_t*)&Kt[jt * 16 + l15][ks * 32 + quad * 8];
                St[0][jt] = __builtin_amdgcn_mfma_f32_16x16x32_f16(a, qfrag[0][ks], St[0][jt], 0, 0, 0);
                St[1][jt] = __builtin_amdgcn_mfma_f32_16x16x32_f16(a, qfrag[1][ks], St[1][jt], 0, 0, 0);
            }

        // ---- online softmax ----
        half4_t apv[2][4];
        float alpha[2];
        for (int mt = 0; mt < 2; ++mt) {
            float mx = St[mt][0][0];
            for (int jt = 0; jt < 4; ++jt)
                for (int r = 0; r < 4; ++r) mx = fmaxf(mx, St[mt][jt][r]);
            mx = fmaxf(mx, __shfl_xor(mx, 16));
            mx = fmaxf(mx, __shfl_xor(mx, 32));
            float mnew = fmaxf(m_run[mt], mx);
            alpha[mt] = __builtin_amdgcn_exp2f(m_run[mt] - mnew);
            m_run[mt] = mnew;
            float ps = 0.f;
            for (int jt = 0; jt < 4; ++jt) {
                float p0 = __builtin_amdgcn_exp2f(St[mt][jt][0] - mnew);
                float p1 = __builtin_amdgcn_exp2f(St[mt][jt][1] - mnew);
                float p2 = __builtin_amdgcn_exp2f(St[mt][jt][2] - mnew);
                float p3 = __builtin_amdgcn_exp2f(St[mt][jt][3] - mnew);
                ps += (p0 + p1) + (p2 + p3);
                apv[mt][jt][0] = (_Float16)p0;
                apv[mt][jt][1] = (_Float16)p1;
                apv[mt][jt][2] = (_Float16)p2;
                apv[mt][jt][3] = (_Float16)p3;
            }
            ps += __shfl_xor(ps, 16);
            ps += __shfl_xor(ps, 32);
            l_run[mt] = l_run[mt] * alpha[mt] + ps;
        }
        for (int mt = 0; mt < 2; ++mt) {
            float aT[4];
            for (int r = 0; r < 4; ++r)
                aT[r] = __shfl(alpha[mt], quad * 4 + r);
            for (int nt = 0; nt < 8; ++nt)
                for (int r = 0; r < 4; ++r) acc[mt][nt][r] *= aT[r];
        }

        // ---- O += P V via 16x16x16; b128 V reads, lo/hi half4 per jt pair ----
        for (int pr = 0; pr < 2; ++pr) {
            for (int nt = 0; nt < 8; ++nt) {
                half8_t bb = *(const half8_t*)&Vt[nt * 16 + l15][pr * 32 + quad * 8];
                half4_t b0, b1;
                b0[0] = bb[0]; b0[1] = bb[1]; b0[2] = bb[2]; b0[3] = bb[3];
                b1[0] = bb[4]; b1[1] = bb[5]; b1[2] = bb[6]; b1[3] = bb[7];
                int jt0 = pr * 2, jt1 = pr * 2 + 1;
                acc[0][nt] = __builtin_amdgcn_mfma_f32_16x16x16f16(apv[0][jt0], b0, acc[0][nt], 0, 0, 0);
                acc[1][nt] = __builtin_amdgcn_mfma_f32_16x16x16f16(apv[1][jt0], b0, acc[1][nt], 0, 0, 0);
                acc[0][nt] = __builtin_amdgcn_mfma_f32_16x16x16f16(apv[0][jt1], b1, acc[0][nt], 0, 0, 0);
                acc[1][nt] = __builtin_amdgcn_mfma_f32_16x16x16f16(apv[1][jt1], b1, acc[1][nt], 0, 0, 0);
            }
        }
        __syncthreads();
    }

    // ---- finalize: write normalized O (O/l) as fp8 e4m3 (packed pairs), plus m,l ----
    for (int mt = 0; mt < 2; ++mt) {
        if (quad == 0) {
            int iq = rbase + mt * 16 + l15;
            mpart[(size_t)sp * T + iq] = m_run[mt];
            lpart[(size_t)sp * T + iq] = l_run[mt];
        }
        float rinv[4];
        for (int r = 0; r < 4; ++r)
            rinv[r] = 1.0f / __shfl(l_run[mt], quad * 4 + r);
        int i = rbase + mt * 16 + quad * 4;
        for (int nt = 0; nt < 4; ++nt)       // pairs of nt: stores 2 bytes apart? no — pack along r
            ;
        for (int nt = 0; nt < 8; ++nt) {
            // pack r pairs: rows i+0..i+3 are different output rows; pack per-row single value.
            for (int r = 0; r < 4; r += 2) {
                float v0 = acc[mt][nt][r]     * rinv[r];
                float v1 = acc[mt][nt][r + 1] * rinv[r + 1];
                int p0 = __builtin_amdgcn_cvt_pk_fp8_f32(v0, v0, 0, false);
                int p1 = __builtin_amdgcn_cvt_pk_fp8_f32(v1, v1, 0, false);
                Opart[((size_t)sp * T + (i + r))     * D + nt * 16 + l15] = (unsigned char)(p0 & 0xFF);
                Opart[((size_t)sp * T + (i + r + 1)) * D + nt * 16 + l15] = (unsigned char)(p1 & 0xFF);
            }
        }
    }
}

// ---------------------------------------------------------------------------
// merge 8 fp8 normalized split partials -> U_A (fp32), linv[i] = 1/L_i.
// grid 512, block 256
// ---------------------------------------------------------------------------
__global__ void merge_kernel(const unsigned char* __restrict__ Opart, const float* __restrict__ mpart,
                             const float* __restrict__ lpart, float* __restrict__ U_A,
                             float* __restrict__ linv) {
    int t = threadIdx.x;
    int i = blockIdx.x * 16 + (t >> 4);
    int c = t & 15;
    float mp[NSPLIT];
    float mstar = -INFINITY;
    for (int sp = 0; sp < NSPLIT; ++sp) {
        mp[sp] = mpart[(size_t)sp * T + i];
        mstar = fmaxf(mstar, mp[sp]);
    }
    float L = 0.f;
    float u[8];
    for (int k = 0; k < 8; ++k) u[k] = 0.f;
    int d0 = c * 8;
    for (int sp = 0; sp < NSPLIT; ++sp) {
        float w = __builtin_amdgcn_exp2f(mp[sp] - mstar) * lpart[(size_t)sp * T + i];
        L += w;
        uint2 ow = *(const uint2*)(Opart + ((size_t)sp * T + i) * D + d0);
        u[0] += __builtin_amdgcn_cvt_f32_fp8(ow.x, 0) * w;
        u[1] += __builtin_amdgcn_cvt_f32_fp8(ow.x, 1) * w;
        u[2] += __builtin_amdgcn_cvt_f32_fp8(ow.x, 2) * w;
        u[3] += __builtin_amdgcn_cvt_f32_fp8(ow.x, 3) * w;
        u[4] += __builtin_amdgcn_cvt_f32_fp8(ow.y, 0) * w;
        u[5] += __builtin_amdgcn_cvt_f32_fp8(ow.y, 1) * w;
        u[6] += __builtin_amdgcn_cvt_f32_fp8(ow.y, 2) * w;
        u[7] += __builtin_amdgcn_cvt_f32_fp8(ow.y, 3) * w;
    }
    float invL = 1.0f / L;
    float4 s0 = make_float4(u[0] * invL, u[1] * invL, u[2] * invL, u[3] * invL);
    float4 s1 = make_float4(u[4] * invL, u[5] * invL, u[6] * invL, u[7] * invL);
    *(float4*)(U_A + (size_t)i * D + d0) = s0;
    *(float4*)(U_A + (size_t)i * D + d0 + 4) = s1;
    if (c == 0) linv[i] = invL;
}

// ---------------------------------------------------------------------------
// h partials then reduce.  grid 64 / grid 1
// ---------------------------------------------------------------------------
__global__ void hsum_part_kernel(const float* __restrict__ x, const float* __restrict__ linv,
                                 float* __restrict__ hpart) {
    const float* context = x;
    int t = threadIdx.x;
    int d = t & 127, g = t >> 7;
    int i0 = blockIdx.x * 128 + g * 64;
    float s = 0.f;
    for (int k = 0; k < 64; ++k)
        s += context[(size_t)(i0 + k) * D + d] * linv[i0 + k];
    hpart[(size_t)(blockIdx.x * 2 + g) * 128 + d] = s;
}

__global__ void hreduce_kernel(const float* __restrict__ hpart, float* __restrict__ h) {
    int d = threadIdx.x;  // 0..127
    float s = 0.f;
    for (int k = 0; k < 128; ++k) s += hpart[(size_t)k * 128 + d];
    h[d] = s;
}

// ---------------------------------------------------------------------------
// assemble G = [ctx, U_A, ctx*U_A, ctx*h]   grid 4096, block 256, float4/thread
// ---------------------------------------------------------------------------
__global__ void assemble_kernel(const float* __restrict__ x, const float* __restrict__ U_A,
                                const float* __restrict__ h, float* __restrict__ out) {
    const float* context = x;
    int gid = blockIdx.x * 256 + threadIdx.x;
    int base = gid * 4;
    int i = base >> 9;
    int c = base & 511;
    int seg = c >> 7, d = c & 127;
    float4 r;
    if (seg == 0) {
        r = *(const float4*)(context + (size_t)i * D + d);
    } else if (seg == 1) {
        r = *(const float4*)(U_A + (size_t)i * D + d);
    } else if (seg == 2) {
        float4 a = *(const float4*)(context + (size_t)i * D + d);
        float4 b = *(const float4*)(U_A + (size_t)i * D + d);
        r = make_float4(a.x * b.x, a.y * b.y, a.z * b.z, a.w * b.w);
    } else {
        float4 a = *(const float4*)(context + (size_t)i * D + d);
        float4 b = *(const float4*)(h + d);
        r = make_float4(a.x * b.x, a.y * b.y, a.z * b.z, a.w * b.w);
    }
    *(float4*)(out + base) = r;
}

// ---------------------------------------------------------------------------
extern "C" void kernel_launch(void* const* d_in, const int* in_sizes, int n_in,
                              void* d_out, int out_size, void* d_ws, size_t ws_size,
                              hipStream_t stream) {
    const float* x = (const float*)d_in[0];
    const float* kern = (const float*)d_in[1];
    float* out = (float*)d_out;

    char* w = (char*)d_ws;
    size_t off = 0;
    _Float16* q16  = (_Float16*)(w + off); off += (size_t)T * D * 2;   // 2 MB
    _Float16* qT16 = (_Float16*)(w + off); off += (size_t)T * D * 2;   // 2 MB
    _Float16* cm16 = (_Float16*)(w + off); off += (size_t)T * D * 2;   // 2 MB
    float* qq2   = (float*)(w + off); off += (size_t)T * 4;            // 32 KB
    float* mpart = (float*)(w + off); off += (size_t)NSPLIT * T * 4;   // 256 KB
    float* lpart = (float*)(w + off); off += (size_t)NSPLIT * T * 4;   // 256 KB
    float* U_A   = (float*)(w + off); off += (size_t)T * D * 4;        // 4 MB
    float* linv  = (float*)(w + off); off += (size_t)T * 4;            // 32 KB
    float* hpart = (float*)(w + off); off += (size_t)128 * 128 * 4;    // 64 KB
    float* h     = (float*)(w + off); off += (size_t)D * 4;

    // d_out doubles as fp8 split-partial scratch: 8 * T * D * 1B = 8 MB <= 16 MB
    unsigned char* Opart = (unsigned char*)d_out;

    prep_kernel<<<256, 256, 0, stream>>>(x, kern, q16, qT16, cm16, qq2);
    flash_kernel<<<512, 256, 0, stream>>>(q16, qT16, cm16, qq2, Opart, mpart, lpart);
    merge_kernel<<<512, 256, 0, stream>>>(Opart, mpart, lpart, U_A, linv);
    hsum_part_kernel<<<64, 256, 0, stream>>>(x, linv, hpart);
    hreduce_kernel<<<1, 128, 0, stream>>>(hpart, h);
    assemble_kernel<<<4096, 256, 0, stream>>>(x, U_A, h, out);
}